// Round 3
// baseline (1172.211 us; speedup 1.0000x reference)
//
#include <hip/hip_runtime.h>
#include <math.h>

#define TSEQ 1024
#define NH 16
#define HD 64

// ---------------- fp32 GEMM: C = A[M,K] * B[N,K]^T, 64x128 tile, 4x8/thread
// Per-output fma chain is k-ascending, identical to the 128x128 version ->
// bitwise-identical results. M=4096, N=1024, K=1024 hardcoded.
#define GBM 64
#define GBN 128
#define GBK 16

__device__ __forceinline__ void gemm64_core(
    const float* __restrict__ A, const float* __restrict__ B,
    float* __restrict__ C, const int bm, const int bn)
{
  const int K = 1024, N = 1024;
  __shared__ float As[GBK][GBM + 4];
  __shared__ float Bs[GBK][GBN + 4];
  const int tid = threadIdx.x;
  const int tm = (tid >> 4) << 2;   // 16 groups x 4 rows
  const int tn = (tid & 15) << 3;   // 16 groups x 8 cols

  float acc[4][8];
#pragma unroll
  for (int i = 0; i < 4; ++i)
#pragma unroll
    for (int j = 0; j < 8; ++j) acc[i][j] = 0.0f;

  const int lr = tid >> 2;          // 0..63
  const int lc = (tid & 3) << 2;    // 0,4,8,12
  const float* Ap = A + (size_t)(bm + lr) * K + lc;
  const float* Bp = B + (size_t)(bn + lr) * K + lc;

  for (int k0 = 0; k0 < K; k0 += GBK) {
    float4 a0 = *(const float4*)(Ap + k0);
    float4 b0 = *(const float4*)(Bp + k0);
    float4 b1 = *(const float4*)(Bp + (size_t)64 * K + k0);
    As[lc + 0][lr] = a0.x; As[lc + 1][lr] = a0.y; As[lc + 2][lr] = a0.z; As[lc + 3][lr] = a0.w;
    Bs[lc + 0][lr] = b0.x; Bs[lc + 1][lr] = b0.y; Bs[lc + 2][lr] = b0.z; Bs[lc + 3][lr] = b0.w;
    Bs[lc + 0][lr + 64] = b1.x; Bs[lc + 1][lr + 64] = b1.y; Bs[lc + 2][lr + 64] = b1.z; Bs[lc + 3][lr + 64] = b1.w;
    __syncthreads();
#pragma unroll
    for (int kk = 0; kk < GBK; ++kk) {
      float4 av  = *(const float4*)&As[kk][tm];
      float4 bv0 = *(const float4*)&Bs[kk][tn];
      float4 bv1 = *(const float4*)&Bs[kk][tn + 4];
      float a[4] = {av.x, av.y, av.z, av.w};
      float bb[8] = {bv0.x, bv0.y, bv0.z, bv0.w, bv1.x, bv1.y, bv1.z, bv1.w};
#pragma unroll
      for (int i = 0; i < 4; ++i)
#pragma unroll
        for (int j = 0; j < 8; ++j) acc[i][j] = fmaf(a[i], bb[j], acc[i][j]);
    }
    __syncthreads();
  }
#pragma unroll
  for (int i = 0; i < 4; ++i) {
    float* Cp = C + (size_t)(bm + tm + i) * N + bn + tn;
    *(float4*)Cp = make_float4(acc[i][0], acc[i][1], acc[i][2], acc[i][3]);
    *(float4*)(Cp + 4) = make_float4(acc[i][4], acc[i][5], acc[i][6], acc[i][7]);
  }
}

__global__ __launch_bounds__(256) void gemm64_nt(
    const float* __restrict__ A, const float* __restrict__ B, float* __restrict__ C)
{
  gemm64_core(A, B, C, blockIdx.y * GBM, blockIdx.x * GBN);
}

// fused Q/K/V: grid.x = 24, uniform per-block pointer select
__global__ __launch_bounds__(256) void gemm64_qkv(
    const float* __restrict__ x,
    const float* __restrict__ wq, const float* __restrict__ wk, const float* __restrict__ wv,
    float* __restrict__ qy, float* __restrict__ ky, float* __restrict__ vy)
{
  int nb = blockIdx.x;
  const float* B; float* C;
  if (nb < 8)       { B = wq; C = qy; }
  else if (nb < 16) { B = wk; C = ky; nb -= 8; }
  else              { B = wv; C = vy; nb -= 16; }
  gemm64_core(x, B, C, blockIdx.y * GBM, nb * GBN);
}

// ---------------- top-4 |v| sparsify, fused over q/k/v, one wave per vector
__global__ __launch_bounds__(256) void sparsify_top4_3(
    float* __restrict__ qa, float* __restrict__ ka, float* __restrict__ va)
{
  int w = blockIdx.x * 4 + (threadIdx.x >> 6);   // 0..196607
  const int lane = threadIdx.x & 63;
  float* base = (w < 65536) ? qa : (w < 131072) ? ka : va;
  w &= 65535;
  float* p = base + (size_t)w * 64;
  const float v = p[lane];
  float ak = fabsf(v);
  bool sel = false;
#pragma unroll
  for (int it = 0; it < 4; ++it) {
    float bv = ak; int bl = lane;
#pragma unroll
    for (int off = 32; off > 0; off >>= 1) {
      float ov = __shfl_xor(bv, off);
      int   ol = __shfl_xor(bl, off);
      if (ov > bv || (ov == bv && ol < bl)) { bv = ov; bl = ol; }
    }
    if (lane == bl) { sel = true; ak = -1.0f; }
  }
  p[lane] = sel ? v : 0.0f;
}

// ---------------- K relayout: [b,t,h,j] -> KT [bh, j, t] --------------------
__global__ __launch_bounds__(256) void transpose_k(
    const float* __restrict__ Ky, float* __restrict__ KT)
{
  __shared__ float tile[64][65];
  const int bh = blockIdx.y;
  const int b = bh >> 4, h = bh & 15;
  const int t0 = blockIdx.x * 64;
  const int tid = threadIdx.x;
  {
    const int j = tid & 63, r = tid >> 6;
#pragma unroll
    for (int i = 0; i < 16; ++i) {
      const int tl = r * 16 + i;
      tile[tl][j] = Ky[(size_t)(b * TSEQ + t0 + tl) * 1024 + h * HD + j];
    }
  }
  __syncthreads();
  {
    const int tl = tid & 63, jr = tid >> 6;
#pragma unroll
    for (int i = 0; i < 16; ++i) {
      const int jl = jr * 16 + i;
      KT[((size_t)(bh * HD + jl)) * TSEQ + t0 + tl] = tile[tl][jl];
    }
  }
}

// ---------------- attention: one block per (q, bh), compaction-based --------
__device__ __forceinline__ unsigned mono_key(float f) {
  unsigned b = __float_as_uint(f);
  return (b & 0x80000000u) ? ~b : (b | 0x80000000u);
}

__global__ __launch_bounds__(256) void attn_sparse(
    const float* __restrict__ Qy, const float* __restrict__ KT,
    const float* __restrict__ Vy, float* __restrict__ Oy)
{
  const int q  = blockIdx.x;
  const int bh = blockIdx.y;
  const int b  = bh >> 4;
  const int h  = bh & 15;
  const int tid  = threadIdx.x;
  const int lane = tid & 63;
  const int wid  = tid >> 6;

  __shared__ unsigned long long pseg[4][256];  // positive (then negative) keys
  __shared__ int   zseg[4][64];                // first-64 zero indices per wave
  __shared__ int   c_pos[4], c_zst[4], c_zt[4];
  __shared__ float redf[4];
  __shared__ float nzv[4];
  __shared__ int   nzi[4];
  __shared__ int   s_nnz;
  __shared__ int   s_nsel;
  __shared__ int   sel_k[64];
  __shared__ float sel_p[64];
  __shared__ float oacc[4][64];
  __shared__ float s_z;

  // extract <=4 nonzeros of q (index order, deterministic)
  if (wid == 0) {
    float v = Qy[((size_t)(b * TSEQ + q)) * 1024 + h * HD + lane];
    unsigned long long mk = __ballot(v != 0.0f);
    if (v != 0.0f) {
      int rk = (int)__popcll(mk & ((1ull << lane) - 1ull));
      if (rk < 4) { nzi[rk] = lane; nzv[rk] = v; }
    }
    if (lane == 0) { int c = (int)__popcll(mk); s_nnz = c < 4 ? c : 4; }
  }
  __syncthreads();
  const int nnz = s_nnz;
  const int nvalid = q + 1;
  const float* ktb = KT + (size_t)bh * HD * TSEQ;

  if (nvalid <= 64) {
    // all valid k selected; wave 0 does everything
    if (wid == 0) {
      float s = -INFINITY;
      if (lane < nvalid) {
        s = 0.0f;
        for (int j = 0; j < nnz; ++j) s += nzv[j] * ktb[(size_t)nzi[j] * TSEQ + lane];
        s *= 0.125f;
      }
      float m = s;
#pragma unroll
      for (int off = 32; off; off >>= 1) m = fmaxf(m, __shfl_xor(m, off));
      if (lane < nvalid) { sel_k[lane] = lane; sel_p[lane] = __expf(s - m); }
      if (lane == 0) s_nsel = nvalid;
    }
  } else {
    const int cs = (nvalid + 3) >> 2;          // contiguous range per wave
    const int lo = wid * cs;
    const int hi = min(lo + cs, nvalid);
    const unsigned long long lml = (1ull << lane) - 1ull;

    int cp = 0, czs = 0, czt = 0;
    float mloc = -INFINITY;
    for (int k0 = lo; k0 < hi; k0 += 64) {
      const int k = k0 + lane;
      const bool val = (k < hi);
      float s = 0.0f;
      if (val) {
        for (int j = 0; j < nnz; ++j) s += nzv[j] * ktb[(size_t)nzi[j] * TSEQ + k];
        s *= 0.125f;
        mloc = fmaxf(mloc, s);
      }
      unsigned u = mono_key(s);
      if (u == 0x7fffffffu) u = 0x80000000u;   // -0 -> +0 (jax: zeros all equal)
      const bool isp = val && (u > 0x80000000u);
      const bool isz = val && (u == 0x80000000u);
      unsigned long long mp = __ballot(isp);
      unsigned long long mz = __ballot(isz);
      if (isp)
        pseg[wid][cp + (int)__popcll(mp & lml)] =
            ((unsigned long long)u << 32) | (unsigned)(1023 - k);
      if (isz) {
        const int o = czs + (int)__popcll(mz & lml);
        if (o < 64) zseg[wid][o] = k;
      }
      cp += (int)__popcll(mp);
      const int zc = (int)__popcll(mz);
      czt += zc;
      czs = min(czs + zc, 64);
    }
#pragma unroll
    for (int off = 32; off; off >>= 1) mloc = fmaxf(mloc, __shfl_xor(mloc, off));
    if (lane == 0) { c_pos[wid] = cp; c_zst[wid] = czs; c_zt[wid] = czt; redf[wid] = mloc; }
    __syncthreads();

    const int npos = c_pos[0] + c_pos[1] + c_pos[2] + c_pos[3];
    const int zt   = c_zt[0] + c_zt[1] + c_zt[2] + c_zt[3];
    const float m  = fmaxf(fmaxf(redf[0], redf[1]), fmaxf(redf[2], redf[3]));

    if (npos > 64) {
      // exact rank-select of top-64 positives; 64-bit keys are all distinct,
      // embed (1023-k) so rank order == value desc, index asc (jax tie rule)
      unsigned long long myk[4]; int nown = 0;
      const int cw = c_pos[wid];
      for (int j = lane; j < cw; j += 64) myk[nown++] = pseg[wid][j];
      int rank[4] = {0, 0, 0, 0};
      for (int w2 = 0; w2 < 4; ++w2) {
        const int c2 = c_pos[w2];
        for (int j2 = 0; j2 < c2; ++j2) {
          const unsigned long long kk = pseg[w2][j2];   // broadcast read
          for (int s2 = 0; s2 < nown; ++s2) rank[s2] += (kk > myk[s2]) ? 1 : 0;
        }
      }
      for (int s2 = 0; s2 < nown; ++s2) {
        if (rank[s2] < 64) {
          const int k = 1023 - (int)(myk[s2] & 0xffffffffull);
          const float sv = __uint_as_float((unsigned)(myk[s2] >> 32) & 0x7fffffffu);
          sel_k[rank[s2]] = k;
          sel_p[rank[s2]] = __expf(sv - m);
        }
      }
      if (tid == 0) s_nsel = 64;
    } else {
      // all positives selected (c_pos[wid] <= npos <= 64 -> lane covers)
      int poff = 0;
      for (int w2 = 0; w2 < wid; ++w2) poff += c_pos[w2];
      if (lane < c_pos[wid]) {
        const unsigned long long kk = pseg[wid][lane];
        const int k = 1023 - (int)(kk & 0xffffffffull);
        const float sv = __uint_as_float((unsigned)(kk >> 32) & 0x7fffffffu);
        sel_k[poff + lane] = k;
        sel_p[poff + lane] = __expf(sv - m);
      }
      const float ezm = __expf(-m);
      if (npos + zt >= 64) {
        // zeros fill the quota in global index order (stored-prefix is exact
        // because quota <= 64 and each wave stores its first 64 zeros)
        const int quota = 64 - npos;
        int zoff = 0;
        for (int w2 = 0; w2 < wid; ++w2) zoff += c_zst[w2];
        if (lane < c_zst[wid]) {
          const int r = zoff + lane;
          if (r < quota) { sel_k[npos + r] = zseg[wid][lane]; sel_p[npos + r] = ezm; }
        }
        if (tid == 0) s_nsel = 64;
      } else {
        // rare: boundary dips into negatives. all zeros stored (zt < 64).
        int zoff = 0;
        for (int w2 = 0; w2 < wid; ++w2) zoff += c_zt[w2];
        if (lane < c_zt[wid]) {
          sel_k[npos + zoff + lane] = zseg[wid][lane];
          sel_p[npos + zoff + lane] = ezm;
        }
        const int need = 64 - npos - zt;
        __syncthreads();                 // positives consumed; reuse pseg
        int cn = 0;
        for (int k0 = lo; k0 < hi; k0 += 64) {
          const int k = k0 + lane;
          const bool val = (k < hi);
          float s = 0.0f;
          if (val) {
            for (int j = 0; j < nnz; ++j) s += nzv[j] * ktb[(size_t)nzi[j] * TSEQ + k];
            s *= 0.125f;
          }
          unsigned u = mono_key(s);
          if (u == 0x7fffffffu) u = 0x80000000u;
          const bool isn = val && (u < 0x80000000u);
          unsigned long long mn = __ballot(isn);
          if (isn)
            pseg[wid][cn + (int)__popcll(mn & lml)] =
                ((unsigned long long)u << 32) | (unsigned)(1023 - k);
          cn += (int)__popcll(mn);
        }
        if (lane == 0) c_pos[wid] = cn;
        __syncthreads();
        unsigned long long myk[4]; int nown = 0;
        const int cw = c_pos[wid];
        for (int j = lane; j < cw; j += 64) myk[nown++] = pseg[wid][j];
        int rank[4] = {0, 0, 0, 0};
        for (int w2 = 0; w2 < 4; ++w2) {
          const int c2 = c_pos[w2];
          for (int j2 = 0; j2 < c2; ++j2) {
            const unsigned long long kk = pseg[w2][j2];
            for (int s2 = 0; s2 < nown; ++s2) rank[s2] += (kk > myk[s2]) ? 1 : 0;
          }
        }
        for (int s2 = 0; s2 < nown; ++s2) {
          if (rank[s2] < need) {
            const int k = 1023 - (int)(myk[s2] & 0xffffffffull);
            const float sv = __uint_as_float(~(unsigned)(myk[s2] >> 32)); // invert mono (negative)
            sel_k[npos + zt + rank[s2]] = k;
            sel_p[npos + zt + rank[s2]] = __expf(sv - m);
          }
        }
        if (tid == 0) s_nsel = 64;
      }
    }
  }
  __syncthreads();
  const int nsel = s_nsel;
  if (wid == 0) {
    float p = (lane < nsel) ? sel_p[lane] : 0.0f;
#pragma unroll
    for (int off = 32; off; off >>= 1) p += __shfl_xor(p, off);
    if (lane == 0) s_z = p;
  }
  // epilogue: out[d] = sum_sel p * V[k][d] / Z ; 4 waves strided over entries
  float acc = 0.0f;
  const float* vb = Vy + ((size_t)b * TSEQ) * 1024 + h * HD + lane;
  for (int s2 = wid; s2 < nsel; s2 += 4)
    acc += sel_p[s2] * vb[(size_t)sel_k[s2] * 1024];
  oacc[wid][lane] = acc;
  __syncthreads();
  if (wid == 0) {
    const float r = (oacc[0][lane] + oacc[1][lane]) + (oacc[2][lane] + oacc[3][lane]);
    Oy[((size_t)(b * TSEQ + q)) * 1024 + h * HD + lane] = r / s_z;
  }
}

// ---------------- launch -----------------------------------------------------
extern "C" void kernel_launch(void* const* d_in, const int* in_sizes, int n_in,
                              void* d_out, int out_size, void* d_ws, size_t ws_size,
                              hipStream_t stream) {
  (void)in_sizes; (void)n_in; (void)out_size; (void)ws_size;
  const float* x  = (const float*)d_in[0];
  const float* wq = (const float*)d_in[1];
  const float* wk = (const float*)d_in[2];
  const float* wv = (const float*)d_in[3];
  const float* wo = (const float*)d_in[4];
  float* out = (float*)d_out;

  float* ws = (float*)d_ws;
  const size_t SZ = (size_t)4096 * 1024;   // 4M floats per buffer
  float* qy = ws;
  float* kyb = ws + SZ;
  float* vy = ws + 2 * SZ;
  float* kt = ws + 3 * SZ;
  float* oy = kyb;                         // kyb dead after transpose

  gemm64_qkv<<<dim3(24, 64), 256, 0, stream>>>(x, wq, wk, wv, qy, kyb, vy);

  sparsify_top4_3<<<196608 / 4, 256, 0, stream>>>(qy, kyb, vy);

  transpose_k<<<dim3(TSEQ / 64, 64), 256, 0, stream>>>(kyb, kt);

  attn_sparse<<<dim3(TSEQ, 64), 256, 0, stream>>>(qy, kt, vy, oy);

  gemm64_nt<<<dim3(8, 64), 256, 0, stream>>>(oy, wo, out);
}

// Round 4
// 943.537 us; speedup vs baseline: 1.2424x; 1.2424x over previous
//
#include <hip/hip_runtime.h>
#include <math.h>

#define TSEQ 1024
#define NH 16
#define HD 64

// ---------------- fp32 GEMM: C = A[M,K] * B[N,K]^T, 64x128 tile, 4x8/thread
#define GBM 64
#define GBN 128
#define GBK 16

__device__ __forceinline__ void gemm64_core(
    const float* __restrict__ A, const float* __restrict__ B,
    float* __restrict__ C, const int bm, const int bn)
{
  const int K = 1024, N = 1024;
  __shared__ float As[GBK][GBM + 4];
  __shared__ float Bs[GBK][GBN + 4];
  const int tid = threadIdx.x;
  const int tm = (tid >> 4) << 2;   // 16 groups x 4 rows
  const int tn = (tid & 15) << 3;   // 16 groups x 8 cols

  float acc[4][8];
#pragma unroll
  for (int i = 0; i < 4; ++i)
#pragma unroll
    for (int j = 0; j < 8; ++j) acc[i][j] = 0.0f;

  const int lr = tid >> 2;          // 0..63
  const int lc = (tid & 3) << 2;    // 0,4,8,12
  const float* Ap = A + (size_t)(bm + lr) * K + lc;
  const float* Bp = B + (size_t)(bn + lr) * K + lc;

  for (int k0 = 0; k0 < K; k0 += GBK) {
    float4 a0 = *(const float4*)(Ap + k0);
    float4 b0 = *(const float4*)(Bp + k0);
    float4 b1 = *(const float4*)(Bp + (size_t)64 * K + k0);
    As[lc + 0][lr] = a0.x; As[lc + 1][lr] = a0.y; As[lc + 2][lr] = a0.z; As[lc + 3][lr] = a0.w;
    Bs[lc + 0][lr] = b0.x; Bs[lc + 1][lr] = b0.y; Bs[lc + 2][lr] = b0.z; Bs[lc + 3][lr] = b0.w;
    Bs[lc + 0][lr + 64] = b1.x; Bs[lc + 1][lr + 64] = b1.y; Bs[lc + 2][lr + 64] = b1.z; Bs[lc + 3][lr + 64] = b1.w;
    __syncthreads();
#pragma unroll
    for (int kk = 0; kk < GBK; ++kk) {
      float4 av  = *(const float4*)&As[kk][tm];
      float4 bv0 = *(const float4*)&Bs[kk][tn];
      float4 bv1 = *(const float4*)&Bs[kk][tn + 4];
      float a[4] = {av.x, av.y, av.z, av.w};
      float bb[8] = {bv0.x, bv0.y, bv0.z, bv0.w, bv1.x, bv1.y, bv1.z, bv1.w};
#pragma unroll
      for (int i = 0; i < 4; ++i)
#pragma unroll
        for (int j = 0; j < 8; ++j) acc[i][j] = fmaf(a[i], bb[j], acc[i][j]);
    }
    __syncthreads();
  }
#pragma unroll
  for (int i = 0; i < 4; ++i) {
    float* Cp = C + (size_t)(bm + tm + i) * N + bn + tn;
    *(float4*)Cp = make_float4(acc[i][0], acc[i][1], acc[i][2], acc[i][3]);
    *(float4*)(Cp + 4) = make_float4(acc[i][4], acc[i][5], acc[i][6], acc[i][7]);
  }
}

__global__ __launch_bounds__(256) void gemm64_nt(
    const float* __restrict__ A, const float* __restrict__ B, float* __restrict__ C)
{
  gemm64_core(A, B, C, blockIdx.y * GBM, blockIdx.x * GBN);
}

__global__ __launch_bounds__(256) void gemm64_qkv(
    const float* __restrict__ x,
    const float* __restrict__ wq, const float* __restrict__ wk, const float* __restrict__ wv,
    float* __restrict__ qy, float* __restrict__ ky, float* __restrict__ vy)
{
  int nb = blockIdx.x;
  const float* B; float* C;
  if (nb < 8)       { B = wq; C = qy; }
  else if (nb < 16) { B = wk; C = ky; nb -= 8; }
  else              { B = wv; C = vy; nb -= 16; }
  gemm64_core(x, B, C, blockIdx.y * GBM, nb * GBN);
}

// ---------------- top-4 |v| sparsify, fused over q/k/v, one wave per vector
__global__ __launch_bounds__(256) void sparsify_top4_3(
    float* __restrict__ qa, float* __restrict__ ka, float* __restrict__ va)
{
  int w = blockIdx.x * 4 + (threadIdx.x >> 6);   // 0..196607
  const int lane = threadIdx.x & 63;
  float* base = (w < 65536) ? qa : (w < 131072) ? ka : va;
  w &= 65535;
  float* p = base + (size_t)w * 64;
  const float v = p[lane];
  float ak = fabsf(v);
  bool sel = false;
#pragma unroll
  for (int it = 0; it < 4; ++it) {
    float bv = ak; int bl = lane;
#pragma unroll
    for (int off = 32; off > 0; off >>= 1) {
      float ov = __shfl_xor(bv, off);
      int   ol = __shfl_xor(bl, off);
      if (ov > bv || (ov == bv && ol < bl)) { bv = ov; bl = ol; }
    }
    if (lane == bl) { sel = true; ak = -1.0f; }
  }
  p[lane] = sel ? v : 0.0f;
}

// ---------------- K relayout: [b,t,h,j] -> KT [bh, j, t] --------------------
__global__ __launch_bounds__(256) void transpose_k(
    const float* __restrict__ Ky, float* __restrict__ KT)
{
  __shared__ float tile[64][65];
  const int bh = blockIdx.y;
  const int b = bh >> 4, h = bh & 15;
  const int t0 = blockIdx.x * 64;
  const int tid = threadIdx.x;
  {
    const int j = tid & 63, r = tid >> 6;
#pragma unroll
    for (int i = 0; i < 16; ++i) {
      const int tl = r * 16 + i;
      tile[tl][j] = Ky[(size_t)(b * TSEQ + t0 + tl) * 1024 + h * HD + j];
    }
  }
  __syncthreads();
  {
    const int tl = tid & 63, jr = tid >> 6;
#pragma unroll
    for (int i = 0; i < 16; ++i) {
      const int jl = jr * 16 + i;
      KT[((size_t)(bh * HD + jl)) * TSEQ + t0 + tl] = tile[tl][jl];
    }
  }
}

// ---------------- attention ---------------------------------------------------
__device__ __forceinline__ unsigned mono_key(float f) {
  unsigned b = __float_as_uint(f);
  return (b & 0x80000000u) ? ~b : (b | 0x80000000u);
}

// Exact rank-select over index-ordered allk[0..nall) (keys: hi32 = mono score,
// lo32 = k). Select hi32 > t_u plus the first need_eq (array order) == t_u;
// write (k, exp(s-m)) into sel_k/sel_p at obase... No local arrays (scratch!).
__device__ __forceinline__ void radix_sel_write(
    unsigned long long* allk, int nall, int target,
    int* hist, unsigned* p_pref, int* p_rem, int* wtot, int* wtot2,
    int* p_eqbase, int* p_wbase,
    int* sel_k, float* sel_p, int obase, bool neg, float m,
    int tid, int lane, int wid)
{
  if (tid == 0) { *p_rem = target; *p_pref = 0u; }
  __syncthreads();
  for (int pass = 0; pass < 4; ++pass) {
    const int shift = 24 - 8 * pass;
    hist[tid] = 0;
    __syncthreads();
    const unsigned pref = *p_pref;
    for (int t0 = 0; t0 < nall; t0 += 256) {
      const int t = t0 + tid;
      bool part = (t < nall);
      const unsigned u = part ? (unsigned)(allk[t] >> 32) : 0u;
      if (pass > 0) part = part && ((u >> (shift + 8)) == (pref >> (shift + 8)));
      const unsigned digit = (u >> shift) & 255u;
      if (part) {
        unsigned long long mm = __ballot(true);
#pragma unroll
        for (int bit = 0; bit < 8; ++bit) {
          unsigned long long bb = __ballot((int)((digit >> bit) & 1u));
          mm &= ((digit >> bit) & 1u) ? bb : ~bb;
        }
        if (lane == __ffsll((unsigned long long)mm) - 1)
          atomicAdd(&hist[digit], (int)__popcll(mm));
      }
    }
    __syncthreads();
    if (wid == 0) {
      const int d0 = lane << 2;
      const int c0 = hist[d0], c1 = hist[d0 + 1], c2 = hist[d0 + 2], c3 = hist[d0 + 3];
      const int sum = c0 + c1 + c2 + c3;
      int S = sum;
#pragma unroll
      for (int off = 1; off < 64; off <<= 1) {
        int t = __shfl_down(S, off);
        if (lane + off < 64) S += t;
      }
      const int above = S - sum;
      const int cg3 = above;
      const int cg2 = above + c3;
      const int cg1 = above + c3 + c2;
      const int cg0 = above + c3 + c2 + c1;
      const int rem = *p_rem;
      if (cg0 < rem && rem <= cg0 + c0) { *p_pref = pref | ((unsigned)(d0 + 0) << shift); *p_rem = rem - cg0; }
      if (cg1 < rem && rem <= cg1 + c1) { *p_pref = pref | ((unsigned)(d0 + 1) << shift); *p_rem = rem - cg1; }
      if (cg2 < rem && rem <= cg2 + c2) { *p_pref = pref | ((unsigned)(d0 + 2) << shift); *p_rem = rem - cg2; }
      if (cg3 < rem && rem <= cg3 + c3) { *p_pref = pref | ((unsigned)(d0 + 3) << shift); *p_rem = rem - cg3; }
    }
    __syncthreads();
  }
  const unsigned t_u = *p_pref;
  const int need_eq = *p_rem;
  if (tid == 0) { *p_eqbase = 0; *p_wbase = 0; }
  __syncthreads();
  for (int t0 = 0; t0 < nall; t0 += 256) {
    const int t = t0 + tid;
    const bool val = (t < nall);
    const unsigned long long kk = val ? allk[t] : 0ull;
    const unsigned u = (unsigned)(kk >> 32);
    const int eq = (val && u == t_u) ? 1 : 0;
    int ceq = eq;
#pragma unroll
    for (int off = 1; off < 64; off <<= 1) { int x = __shfl_up(ceq, off); if (lane >= off) ceq += x; }
    if (lane == 63) wtot[wid] = ceq;
    __syncthreads();
    int wo = 0;
    for (int w = 0; w < wid; ++w) wo += wtot[w];
    const int eqrank = *p_eqbase + wo + ceq - eq;
    const int sf = (val && ((u > t_u) || (eq && eqrank < need_eq))) ? 1 : 0;
    int csf = sf;
#pragma unroll
    for (int off = 1; off < 64; off <<= 1) { int x = __shfl_up(csf, off); if (lane >= off) csf += x; }
    if (lane == 63) wtot2[wid] = csf;
    __syncthreads();
    int wo2 = 0;
    for (int w = 0; w < wid; ++w) wo2 += wtot2[w];
    if (sf) {
      const int pos = *p_wbase + wo2 + csf - sf;
      const int k = (int)(kk & 0xffffffffull);
      const float sv = neg ? __uint_as_float(~u) : __uint_as_float(u & 0x7fffffffu);
      sel_k[obase + pos] = k;
      sel_p[obase + pos] = __expf(sv - m);
    }
    __syncthreads();
    if (tid == 0) {
      *p_eqbase += wtot[0] + wtot[1] + wtot[2] + wtot[3];
      *p_wbase  += wtot2[0] + wtot2[1] + wtot2[2] + wtot2[3];
    }
    __syncthreads();
  }
}

__global__ __launch_bounds__(256) void attn_sparse(
    const float* __restrict__ Qy, const float* __restrict__ KT,
    const float* __restrict__ Vy, float* __restrict__ Oy)
{
  const int q  = blockIdx.x;
  const int bh = blockIdx.y;
  const int b  = bh >> 4;
  const int h  = bh & 15;
  const int tid  = threadIdx.x;
  const int lane = tid & 63;
  const int wid  = tid >> 6;

  __shared__ unsigned long long pseg[4][256];  // per-wave compacted keys
  __shared__ unsigned long long allk[1024];    // merged, global index order
  __shared__ int   zseg[4][64];
  __shared__ int   c_pos[4], c_zst[4], c_zt[4], c_neg[4];
  __shared__ float redf[4];
  __shared__ int   hist[256];
  __shared__ float nzv[4];
  __shared__ int   nzi[4];
  __shared__ int   s_nsel;
  __shared__ unsigned s_pref;
  __shared__ int   s_rem;
  __shared__ int   wtot[4], wtot2[4];
  __shared__ int   s_eqbase, s_wbase;
  __shared__ int   sel_k[64];
  __shared__ float sel_p[64];
  __shared__ float oacc[4][64];
  __shared__ float s_z;

  // extract <=4 nonzeros of q, padded to 4 with zeros (pads contribute +-0)
  if (wid == 0) {
    if (lane < 4) { nzv[lane] = 0.0f; nzi[lane] = 0; }
    float v = Qy[((size_t)(b * TSEQ + q)) * 1024 + h * HD + lane];
    unsigned long long mk = __ballot(v != 0.0f);
    if (v != 0.0f) {
      int rk = (int)__popcll(mk & ((1ull << lane) - 1ull));
      if (rk < 4) { nzi[rk] = lane; nzv[rk] = v; }
    }
  }
  __syncthreads();
  const int nvalid = q + 1;
  const float* ktb = KT + (size_t)bh * HD * TSEQ;

  if (nvalid <= 64) {
    if (wid == 0) {
      float s = -INFINITY;
      if (lane < nvalid) {
        s = 0.0f;
#pragma unroll
        for (int j = 0; j < 4; ++j) s += nzv[j] * ktb[(size_t)nzi[j] * TSEQ + lane];
        s *= 0.125f;
      }
      float m = s;
#pragma unroll
      for (int off = 32; off; off >>= 1) m = fmaxf(m, __shfl_xor(m, off));
      if (lane < nvalid) { sel_k[lane] = lane; sel_p[lane] = __expf(s - m); }
      if (lane == 0) s_nsel = nvalid;
    }
  } else {
    const int cs = (nvalid + 3) >> 2;          // contiguous range per wave
    const int lo = wid * cs;
    const int hi = min(lo + cs, nvalid);
    const unsigned long long lml = (1ull << lane) - 1ull;

    int cp = 0, czs = 0, czt = 0;
    float mloc = -INFINITY;
    for (int k0 = lo; k0 < hi; k0 += 64) {
      const int k = k0 + lane;
      const bool val = (k < hi);
      float s = 0.0f;
      if (val) {
#pragma unroll
        for (int j = 0; j < 4; ++j) s += nzv[j] * ktb[(size_t)nzi[j] * TSEQ + k];
        s *= 0.125f;
        mloc = fmaxf(mloc, s);
      }
      unsigned u = mono_key(s);
      if (u == 0x7fffffffu) u = 0x80000000u;   // -0 -> +0 (ties with +0, idx order)
      const bool isp = val && (u > 0x80000000u);
      const bool isz = val && (u == 0x80000000u);
      unsigned long long mp = __ballot(isp);
      unsigned long long mz = __ballot(isz);
      if (isp)
        pseg[wid][cp + (int)__popcll(mp & lml)] = ((unsigned long long)u << 32) | (unsigned)k;
      if (isz) {
        const int o = czs + (int)__popcll(mz & lml);
        if (o < 64) zseg[wid][o] = k;
      }
      cp += (int)__popcll(mp);
      const int zc = (int)__popcll(mz);
      czt += zc;
      czs = min(czs + zc, 64);
    }
#pragma unroll
    for (int off = 32; off; off >>= 1) mloc = fmaxf(mloc, __shfl_xor(mloc, off));
    if (lane == 0) { c_pos[wid] = cp; c_zst[wid] = czs; c_zt[wid] = czt; redf[wid] = mloc; }
    __syncthreads();

    const int npos = c_pos[0] + c_pos[1] + c_pos[2] + c_pos[3];
    const int zt   = c_zt[0] + c_zt[1] + c_zt[2] + c_zt[3];
    const float m  = fmaxf(fmaxf(redf[0], redf[1]), fmaxf(redf[2], redf[3]));

    if (npos > 64) {
      // merge positives into allk (global index order), radix-select top-64
      int poff = 0;
      for (int w2 = 0; w2 < wid; ++w2) poff += c_pos[w2];
      for (int j = lane; j < c_pos[wid]; j += 64) allk[poff + j] = pseg[wid][j];
      if (tid == 0) s_nsel = 64;
      __syncthreads();
      radix_sel_write(allk, npos, 64, hist, &s_pref, &s_rem, wtot, wtot2,
                      &s_eqbase, &s_wbase, sel_k, sel_p, 0, false, m,
                      tid, lane, wid);
    } else {
      // all positives selected
      int poff = 0;
      for (int w2 = 0; w2 < wid; ++w2) poff += c_pos[w2];
      if (lane < c_pos[wid]) {
        const unsigned long long kk = pseg[wid][lane];
        sel_k[poff + lane] = (int)(kk & 0xffffffffull);
        sel_p[poff + lane] = __expf(__uint_as_float((unsigned)(kk >> 32) & 0x7fffffffu) - m);
      }
      const float ezm = __expf(-m);
      if (npos + zt >= 64) {
        // zeros fill the quota in global index order
        const int quota = 64 - npos;
        int zoff = 0;
        for (int w2 = 0; w2 < wid; ++w2) zoff += c_zst[w2];
        if (lane < c_zst[wid]) {
          const int r = zoff + lane;
          if (r < quota) { sel_k[npos + r] = zseg[wid][lane]; sel_p[npos + r] = ezm; }
        }
        if (tid == 0) s_nsel = 64;
      } else {
        // rare: boundary dips into negatives; all zeros stored (zt < 64)
        int zoff = 0;
        for (int w2 = 0; w2 < wid; ++w2) zoff += c_zt[w2];
        if (lane < c_zt[wid]) {
          sel_k[npos + zoff + lane] = zseg[wid][lane];
          sel_p[npos + zoff + lane] = ezm;
        }
        const int need = 64 - npos - zt;
        if (tid == 0) s_nsel = 64;
        __syncthreads();                 // positives consumed; reuse pseg
        int cn = 0;
        for (int k0 = lo; k0 < hi; k0 += 64) {
          const int k = k0 + lane;
          const bool val = (k < hi);
          float s = 0.0f;
          if (val) {
#pragma unroll
            for (int j = 0; j < 4; ++j) s += nzv[j] * ktb[(size_t)nzi[j] * TSEQ + k];
            s *= 0.125f;
          }
          unsigned u = mono_key(s);
          if (u == 0x7fffffffu) u = 0x80000000u;
          const bool isn = val && (u < 0x80000000u);
          unsigned long long mn = __ballot(isn);
          if (isn)
            pseg[wid][cn + (int)__popcll(mn & lml)] = ((unsigned long long)u << 32) | (unsigned)k;
          cn += (int)__popcll(mn);
        }
        if (lane == 0) c_neg[wid] = cn;
        __syncthreads();
        const int nneg = c_neg[0] + c_neg[1] + c_neg[2] + c_neg[3];
        int noff = 0;
        for (int w2 = 0; w2 < wid; ++w2) noff += c_neg[w2];
        for (int j = lane; j < c_neg[wid]; j += 64) allk[noff + j] = pseg[wid][j];
        __syncthreads();
        radix_sel_write(allk, nneg, need, hist, &s_pref, &s_rem, wtot, wtot2,
                        &s_eqbase, &s_wbase, sel_k, sel_p, npos + zt, true, m,
                        tid, lane, wid);
      }
    }
  }
  __syncthreads();
  const int nsel = s_nsel;
  if (wid == 0) {
    float p = (lane < nsel) ? sel_p[lane] : 0.0f;
#pragma unroll
    for (int off = 32; off; off >>= 1) p += __shfl_xor(p, off);
    if (lane == 0) s_z = p;
  }
  // epilogue: out[d] = sum_sel p * V[k][d] / Z ; 4 waves strided over entries
  float acc = 0.0f;
  const float* vb = Vy + ((size_t)b * TSEQ) * 1024 + h * HD + lane;
  for (int s2 = wid; s2 < nsel; s2 += 4)
    acc += sel_p[s2] * vb[(size_t)sel_k[s2] * 1024];
  oacc[wid][lane] = acc;
  __syncthreads();
  if (wid == 0) {
    const float r = (oacc[0][lane] + oacc[1][lane]) + (oacc[2][lane] + oacc[3][lane]);
    Oy[((size_t)(b * TSEQ + q)) * 1024 + h * HD + lane] = r / s_z;
  }
}

// ---------------- launch -----------------------------------------------------
extern "C" void kernel_launch(void* const* d_in, const int* in_sizes, int n_in,
                              void* d_out, int out_size, void* d_ws, size_t ws_size,
                              hipStream_t stream) {
  (void)in_sizes; (void)n_in; (void)out_size; (void)ws_size;
  const float* x  = (const float*)d_in[0];
  const float* wq = (const float*)d_in[1];
  const float* wk = (const float*)d_in[2];
  const float* wv = (const float*)d_in[3];
  const float* wo = (const float*)d_in[4];
  float* out = (float*)d_out;

  float* ws = (float*)d_ws;
  const size_t SZ = (size_t)4096 * 1024;   // 4M floats per buffer
  float* qy = ws;
  float* kyb = ws + SZ;
  float* vy = ws + 2 * SZ;
  float* kt = ws + 3 * SZ;
  float* oy = kyb;                         // kyb dead after transpose

  gemm64_qkv<<<dim3(24, 64), 256, 0, stream>>>(x, wq, wk, wv, qy, kyb, vy);

  sparsify_top4_3<<<196608 / 4, 256, 0, stream>>>(qy, kyb, vy);

  transpose_k<<<dim3(TSEQ / 64, 64), 256, 0, stream>>>(kyb, kt);

  attn_sparse<<<dim3(TSEQ, 64), 256, 0, stream>>>(qy, kt, vy, oy);

  gemm64_nt<<<dim3(8, 64), 256, 0, stream>>>(oy, wo, out);
}